// Round 7
// baseline (428.690 us; speedup 1.0000x reference)
//
#include <hip/hip_runtime.h>

typedef unsigned short u16;
typedef unsigned int u32;
typedef __attribute__((ext_vector_type(8))) short short8v;   // 8 bf16 MFMA frag
typedef __attribute__((ext_vector_type(4))) float f32x4;
typedef __attribute__((ext_vector_type(2))) float f32x2;
typedef __attribute__((ext_vector_type(4))) unsigned int uint4v;
typedef __attribute__((ext_vector_type(2))) unsigned int uint2v;
typedef __attribute__((ext_vector_type(8))) unsigned short us8;
typedef __attribute__((ext_vector_type(4))) unsigned short us4;

#define B_   4
#define S_   19950
#define C_   256
#define NH   8
#define DH   32
#define BS_  (B_*S_)          // 79800

#define BM 128
#define BN 128
#define BK 64                 // K-tile per LDS buffer (4 iters over K=256)

__device__ __forceinline__ float bf2f(u16 u){ u32 x=((u32)u)<<16; float f; __builtin_memcpy(&f,&x,4); return f; }
__device__ __forceinline__ u16 f2bf(float f){ u32 x; __builtin_memcpy(&x,&f,4); x += 0x7fffu + ((x>>16)&1u); return (u16)(x>>16); }
__device__ __forceinline__ u32 cvtpk(float a, float b){ u32 r; asm("v_cvt_pk_bf16_f32 %0, %1, %2" : "=v"(r) : "v"(a), "v"(b)); return r; }
__device__ __forceinline__ f32x2 pkfma(f32x2 a, f32x2 b, f32x2 d){
  asm("v_pk_fma_f32 %0, %1, %2, %0" : "+v"(d) : "v"(a), "v"(b)); return d;
}
__device__ __forceinline__ f32x2 unpk(u32 p){
  uint2v u; u.x = p<<16; u.y = p & 0xffff0000u; return __builtin_bit_cast(f32x2, u);
}

// ================= MFMA GEMM core: C[M,N] = A[M,256] * W[N,256]^T =================
// MODE 0: A=value f32 -> v bf16 permuted (b,h,s,dh);  MODE 1: A=query f32 -> soff + softmaxed sattn
// MODE 2: A=tmp bf16  -> out f32.
// bf16 double-buffered LDS for BOTH operands (round-2 zero-conflict layout:
// 128B rows of 64 bf16, 16B chunk index XOR (row&7)). Reg-staged: f32 global ->
// cvt_pk_bf16 -> ds_write. Loads for k-tile t+1 issued before compute of t.
template<int MODE>
__device__ __forceinline__ void gemm_core(
    const void* __restrict__ Aany, const float* __restrict__ Wmain,
    const float* __restrict__ Wattn, const float* __restrict__ bmain,
    const float* __restrict__ battn, void* __restrict__ out0, u16* __restrict__ out1)
{
  constexpr int NX = (MODE==1) ? 3 : 2;
  __shared__ u32 AsU[2*4096];   // 32 KB: bf16[2][128 rows][64 k]
  __shared__ u32 BsU[2*4096];   // 32 KB

  const int tid = threadIdx.x;
  const int g = blockIdx.x;
  const int x = (g>>3) % NX;
  const int y = ((g>>3)/NX)*8 + (g&7);   // XCD-paired: col-blocks of one A-panel 8 apart -> same XCD
  const int m0 = y * BM;
  const int n0 = x * BN;
  const int lane = tid & 63;
  const int wid  = tid >> 6;
  const int wm = wid >> 1, wn = wid & 1;
  const int ln15 = lane & 15, ln4 = lane >> 4;

  // staging role: thread covers row sr, k-half skh (32 k of the 64-k tile)
  const int sr = tid >> 1, skh = tid & 1;
  const size_t aRow = (size_t)min(m0 + sr, BS_-1) * C_;
  const float* bRowP;
  if constexpr (MODE==1) {
    const int n = n0 + sr;
    bRowP = (n < 192) ? (Wmain + (size_t)n*C_) : (Wattn + (size_t)(min(n,287)-192)*C_);
  } else {
    bRowP = Wmain + (size_t)(n0 + sr)*C_;
  }

  f32x4 ra[8], rb[8];
  uint4v ra2[4];

  auto loadA = [&](int k0){
    if constexpr (MODE==2) {
      const u16* Ab = (const u16*)Aany;
      #pragma unroll
      for (int j=0;j<4;++j) ra2[j] = *(const uint4v*)(Ab + aRow + k0 + skh*32 + j*8);
    } else {
      const float* Ab = (const float*)Aany;
      #pragma unroll
      for (int j=0;j<8;++j) ra[j] = *(const f32x4*)(Ab + aRow + k0 + skh*32 + j*4);
    }
  };
  auto loadB = [&](int k0){
    #pragma unroll
    for (int j=0;j<8;++j) rb[j] = *(const f32x4*)(bRowP + k0 + skh*32 + j*4);
  };
  auto writeA = [&](int buf){
    u32* base = &AsU[buf*4096 + sr*32];
    #pragma unroll
    for (int j2=0;j2<4;++j2){
      const int c = skh*4 + j2;
      uint4v pk;
      if constexpr (MODE==2) pk = ra2[j2];
      else {
        pk.x = cvtpk(ra[2*j2].x,  ra[2*j2].y);   pk.y = cvtpk(ra[2*j2].z,  ra[2*j2].w);
        pk.z = cvtpk(ra[2*j2+1].x,ra[2*j2+1].y); pk.w = cvtpk(ra[2*j2+1].z,ra[2*j2+1].w);
      }
      *(uint4v*)&base[(c ^ (sr&7))<<2] = pk;
    }
  };
  auto writeB = [&](int buf){
    u32* base = &BsU[buf*4096 + sr*32];
    #pragma unroll
    for (int j2=0;j2<4;++j2){
      const int c = skh*4 + j2;
      uint4v pk;
      pk.x = cvtpk(rb[2*j2].x,  rb[2*j2].y);   pk.y = cvtpk(rb[2*j2].z,  rb[2*j2].w);
      pk.z = cvtpk(rb[2*j2+1].x,rb[2*j2+1].y); pk.w = cvtpk(rb[2*j2+1].z,rb[2*j2+1].w);
      *(uint4v*)&base[(c ^ (sr&7))<<2] = pk;
    }
  };

  f32x4 acc[4][4];
  #pragma unroll
  for (int i=0;i<4;++i){
    #pragma unroll
    for (int j=0;j<4;++j) acc[i][j] = (f32x4){0.f,0.f,0.f,0.f};
  }

  // ---- prologue: fill buf0 ----
  loadA(0); loadB(0);
  writeA(0); writeB(0);
  __syncthreads();

  for (int t=0; t<4; ++t) {
    const int cur = t & 1;
    if (t < 3) { loadA((t+1)*BK); loadB((t+1)*BK); }   // issue next-tile loads early
    // ---- compute current tile: 2 k-sub of 32, 4x4 frags ----
    #pragma unroll
    for (int ks=0; ks<2; ++ks) {
      short8v af[4], bfr[4];
      #pragma unroll
      for (int mi=0;mi<4;++mi){
        const int row = wm*64 + mi*16 + ln15;
        const int c = ks*4 + ln4;
        af[mi] = *(const short8v*)&AsU[cur*4096 + row*32 + ((c ^ (row&7))<<2)];
      }
      #pragma unroll
      for (int ni=0;ni<4;++ni){
        const int row = wn*64 + ni*16 + ln15;
        const int c = ks*4 + ln4;
        bfr[ni] = *(const short8v*)&BsU[cur*4096 + row*32 + ((c ^ (row&7))<<2)];
      }
      #pragma unroll
      for (int mi=0;mi<4;++mi){
        #pragma unroll
        for (int ni=0;ni<4;++ni)
          acc[mi][ni] = __builtin_amdgcn_mfma_f32_16x16x32_bf16(af[mi], bfr[ni], acc[mi][ni], 0, 0, 0);
      }
    }
    if (t < 3) {
      writeA(cur^1); writeB(cur^1);   // cvt + ds_write next tile (waits loads at use)
      __syncthreads();
    }
  }

  // ---- epilogue (validated rounds 2/4/6) ----
  #pragma unroll
  for (int mi=0;mi<4;++mi){
    #pragma unroll
    for (int ni=0;ni<4;++ni){
      const int n = n0 + wn*64 + ni*16 + ln15;
      if (MODE==1 && n >= 288) continue;
      float bias;
      if constexpr (MODE==1) bias = (n < 192) ? bmain[n] : battn[n-192];
      else                   bias = bmain[n];
      if (MODE==1 && n >= 192) {
        #pragma unroll
        for (int j=0;j<4;++j){
          const int m = m0 + wm*64 + mi*16 + ln4*4 + j;
          const float vv = acc[mi][ni][j] + bias;
          float mx = vv;
          mx = fmaxf(mx, __shfl_xor(mx, 1));
          mx = fmaxf(mx, __shfl_xor(mx, 2));
          const float e = __expf(vv - mx);
          float ssum = e;
          ssum += __shfl_xor(ssum, 1);
          ssum += __shfl_xor(ssum, 2);
          if (m < BS_) out1[(size_t)m*96 + (n-192)] = f2bf(e/ssum);
        }
      } else if (MODE==1) {
        u16* soff = (u16*)out0;
        #pragma unroll
        for (int j=0;j<4;++j){
          const int m = m0 + wm*64 + mi*16 + ln4*4 + j;
          if (m < BS_) soff[(size_t)m*192 + n] = f2bf(acc[mi][ni][j] + bias);
        }
      } else if (MODE==0) {
        u16* vout = (u16*)out0;
        const int h = n >> 5, dh = n & 31;
        #pragma unroll
        for (int j=0;j<4;++j){
          const int m = m0 + wm*64 + mi*16 + ln4*4 + j;
          if (m < BS_) {
            const int bq = m / S_, s = m - bq*S_;
            vout[((size_t)(bq*NH+h)*S_ + s)*DH + dh] = f2bf(acc[mi][ni][j] + bias);
          }
        }
      } else {
        float* outp = (float*)out0;
        #pragma unroll
        for (int j=0;j<4;++j){
          const int m = m0 + wm*64 + mi*16 + ln4*4 + j;
          if (m < BS_) outp[(size_t)m*C_ + n] = acc[mi][ni][j] + bias;
        }
      }
    }
  }
}

// Plain (non-template) kernels -> host stubs always emitted.
__global__ __launch_bounds__(256,2) void k_gemm0(const void* __restrict__ A,
    const float* __restrict__ W, const float* __restrict__ b, void* __restrict__ o)
{ gemm_core<0>(A, W, nullptr, b, nullptr, o, nullptr); }

__global__ __launch_bounds__(256,2) void k_gemm1(const void* __restrict__ A,
    const float* __restrict__ Wm, const float* __restrict__ Wa,
    const float* __restrict__ bm, const float* __restrict__ ba,
    void* __restrict__ o0, u16* __restrict__ o1)
{ gemm_core<1>(A, Wm, Wa, bm, ba, o0, o1); }

__global__ __launch_bounds__(256,2) void k_gemm2(const void* __restrict__ A,
    const float* __restrict__ W, const float* __restrict__ b, void* __restrict__ o)
{ gemm_core<2>(A, W, nullptr, b, nullptr, o, nullptr); }

// ================= Sampler v5: 16 ch/thread (2 threads/query), cached loads =================
#define NCH5 156   // ceil(19950/128) chunks of 128 queries

__global__ __launch_bounds__(256) void k_sample5(const u16* __restrict__ v,
    const u16* __restrict__ soff, const u16* __restrict__ sattn,
    const float* __restrict__ refp, u16* __restrict__ tmp)
{
  const int g = blockIdx.x;
  const int xcd = g & 7, inner = g >> 3;      // inner in [0, 4*NCH5)
  const int unit = inner / NCH5;              // 0..3
  const int cidx = inner - unit*NCH5;
  const int bh = xcd*4 + unit;                // 4 (b,h)-slices per XCD, processed unit-major in time
  const int b = bh >> 3, h = bh & 7;
  const int dh0 = (threadIdx.x & 1) * 16;
  const int q = cidx*128 + (threadIdx.x >> 1);
  if (q >= S_) return;
  const size_t r = (size_t)b*S_ + q;
  const float refx = refp[r*2+0], refy = refp[r*2+1];
  const u16* vb = v + (size_t)bh * S_ * DH;

  const u16* sop = soff + r*192 + h*24;
  const u16* sap = sattn + r*96 + h*12;
  us8 so0 = *(const us8*)(sop);
  us8 so1 = *(const us8*)(sop + 8);
  us8 so2 = *(const us8*)(sop + 16);
  us4 sa0 = *(const us4*)(sap);
  us4 sa1 = *(const us4*)(sap + 4);
  us4 sa2 = *(const us4*)(sap + 8);
  u16 soarr[24]; u16 saarr[12];
  #pragma unroll
  for (int i=0;i<8;++i){ soarr[i]=so0[i]; soarr[8+i]=so1[i]; soarr[16+i]=so2[i]; }
  #pragma unroll
  for (int i=0;i<4;++i){ saarr[i]=sa0[i]; saarr[4+i]=sa1[i]; saarr[8+i]=sa2[i]; }

  f32x2 a0=(f32x2){0.f,0.f}, a1=a0, a2=a0, a3=a0, a4=a0, a5=a0, a6=a0, a7=a0;
  const int WLs[3]={152,76,38}, HLs[3]={100,50,25}, STs[3]={0,15200,19000};
  #pragma unroll
  for (int l=0;l<3;++l) {
    const int Wl=WLs[l], Hl=HLs[l];
    const float rxl = refx*(float)Wl - 0.5f;   // ix = ref*W + off - 0.5 (normalizer folded)
    const float ryl = refy*(float)Hl - 0.5f;
    const u16* vbl = vb + (size_t)STs[l]*DH;
    #pragma unroll
    for (int p=0;p<4;++p) {
      const int idx = l*4 + p;
      const float ix = rxl + bf2f(soarr[2*idx+0]);
      const float iy = ryl + bf2f(soarr[2*idx+1]);
      const float aw = bf2f(saarr[idx]);
      const float x0f = floorf(ix), y0f = floorf(iy);
      const float wx1 = ix-x0f, wy1 = iy-y0f;
      const float wx0 = 1.f-wx1, wy0 = 1.f-wy1;
      const int x0 = (int)x0f, y0 = (int)y0f;
      #pragma unroll
      for (int dy=0; dy<2; ++dy) {
        const int yc = y0+dy;
        const bool vy = (yc>=0) && (yc<Hl);
        const int yi = min(max(yc,0),Hl-1);
        const float wyf = aw * (dy?wy1:wy0);
        #pragma unroll
        for (int dx=0; dx<2; ++dx) {
          const int xc = x0+dx;
          const bool vx = (xc>=0) && (xc<Wl);
          const int xi = min(max(xc,0),Wl-1);
          float w = wyf * (dx?wx1:wx0);
          if (!(vx && vy)) w = 0.f;
          f32x2 w2; w2.x = w; w2.y = w;
          const u16* tap = vbl + (size_t)(yi*Wl + xi)*DH + dh0;
          const uint4v ta = *(const uint4v*)(tap);
          const uint4v tb = *(const uint4v*)(tap + 8);
          a0 = pkfma(unpk(ta.x), w2, a0);
          a1 = pkfma(unpk(ta.y), w2, a1);
          a2 = pkfma(unpk(ta.z), w2, a2);
          a3 = pkfma(unpk(ta.w), w2, a3);
          a4 = pkfma(unpk(tb.x), w2, a4);
          a5 = pkfma(unpk(tb.y), w2, a5);
          a6 = pkfma(unpk(tb.z), w2, a6);
          a7 = pkfma(unpk(tb.w), w2, a7);
        }
      }
    }
  }
  uint4v o1, o2;
  o1.x = cvtpk(a0.x, a0.y); o1.y = cvtpk(a1.x, a1.y);
  o1.z = cvtpk(a2.x, a2.y); o1.w = cvtpk(a3.x, a3.y);
  o2.x = cvtpk(a4.x, a4.y); o2.y = cvtpk(a5.x, a5.y);
  o2.z = cvtpk(a6.x, a6.y); o2.w = cvtpk(a7.x, a7.y);
  u16* op = tmp + r*C_ + (size_t)h*DH + dh0;
  *(uint4v*)(op)     = o1;
  *(uint4v*)(op + 8) = o2;
}

extern "C" void kernel_launch(void* const* d_in, const int* in_sizes, int n_in,
                              void* d_out, int out_size, void* d_ws, size_t ws_size,
                              hipStream_t stream) {
  (void)in_sizes; (void)n_in; (void)out_size; (void)ws_size;
  const float* query = (const float*)d_in[0];
  const float* value = (const float*)d_in[1];
  const float* refp  = (const float*)d_in[4];
  const float* W_off = (const float*)d_in[5];
  const float* b_off = (const float*)d_in[6];
  const float* W_attn= (const float*)d_in[7];
  const float* b_attn= (const float*)d_in[8];
  const float* W_val = (const float*)d_in[9];
  const float* b_val = (const float*)d_in[10];
  const float* W_out = (const float*)d_in[11];
  const float* b_out = (const float*)d_in[12];
  float* out = (float*)d_out;

  char* ws = (char*)d_ws;
  constexpr size_t V_BYTES    = (size_t)BS_*C_*2;     // 40.9 MB: v bf16 (b,h,s,dh)
  constexpr size_t SOFF_BYTES = (size_t)BS_*192*2;    // 30.6 MB
  constexpr size_t SATTN_BYTES= (size_t)BS_*96*2;     // 15.3 MB
  u16* v     = (u16*)(ws);
  u16* soff  = (u16*)(ws + V_BYTES);
  u16* sattn = (u16*)(ws + V_BYTES + SOFF_BYTES);
  u16* tmp   = (u16*)(ws + V_BYTES + SOFF_BYTES + SATTN_BYTES);

  dim3 blk(256);
  hipLaunchKernelGGL(k_gemm0, dim3(2*624), blk, 0, stream,
                     (const void*)value, W_val, b_val, (void*)v);
  hipLaunchKernelGGL(k_gemm1, dim3(3*624), blk, 0, stream,
                     (const void*)query, W_off, W_attn, b_off, b_attn,
                     (void*)soff, sattn);
  hipLaunchKernelGGL(k_sample5, dim3(8*4*NCH5), blk, 0, stream, v, soff, sattn, refp, tmp);
  hipLaunchKernelGGL(k_gemm2, dim3(2*624), blk, 0, stream,
                     (const void*)tmp, W_out, b_out, (void*)out);
}

// Round 8
// 307.723 us; speedup vs baseline: 1.3931x; 1.3931x over previous
//
#include <hip/hip_runtime.h>

typedef unsigned short u16;
typedef unsigned int u32;
typedef __attribute__((ext_vector_type(8))) short short8v;   // 8 bf16 MFMA frag
typedef __attribute__((ext_vector_type(4))) float f32x4;
typedef __attribute__((ext_vector_type(2))) float f32x2;
typedef __attribute__((ext_vector_type(4))) unsigned int uint4v;
typedef __attribute__((ext_vector_type(2))) unsigned int uint2v;
typedef __attribute__((ext_vector_type(8))) unsigned short us8;
typedef __attribute__((ext_vector_type(4))) unsigned short us4;

#define B_   4
#define S_   19950
#define C_   256
#define NH   8
#define DH   32
#define BS_  (B_*S_)          // 79800

#define BM 128
#define BN 128
#define BK 64

__device__ __forceinline__ float bf2f(u16 u){ u32 x=((u32)u)<<16; float f; __builtin_memcpy(&f,&x,4); return f; }
__device__ __forceinline__ u16 f2bf(float f){ u32 x; __builtin_memcpy(&x,&f,4); x += 0x7fffu + ((x>>16)&1u); return (u16)(x>>16); }
__device__ __forceinline__ u32 cvtpk(float a, float b){ u32 r; asm("v_cvt_pk_bf16_f32 %0, %1, %2" : "=v"(r) : "v"(a), "v"(b)); return r; }
__device__ __forceinline__ f32x2 pkfma(f32x2 a, f32x2 b, f32x2 d){
  asm("v_pk_fma_f32 %0, %1, %2, %0" : "+v"(d) : "v"(a), "v"(b)); return d;
}
__device__ __forceinline__ f32x2 unpk(u32 p){
  uint2v u; u.x = p<<16; u.y = p & 0xffff0000u; return __builtin_bit_cast(f32x2, u);
}

// ================= MFMA GEMM core (round-4 internals, shared-LDS parameterized) =================
// MODE 0: A=value f32 -> v bf16 permuted (b,h,s,dh);  MODE 1: A=query f32 -> soff + softmaxed sattn
// MODE 2: A=tmp bf16  -> out f32.
// A staged via async global_load_lds; XOR swizzle via inverse-swizzled per-lane SOURCE
// address (LDS dest linear) + same XOR on read. B (L2-hot weights) reg-staged w/ cvt.
template<int MODE>
__device__ __forceinline__ void gemm_core(int g, u32* smem,
    const void* __restrict__ Aany, const float* __restrict__ Wmain,
    const float* __restrict__ Wattn, const float* __restrict__ bmain,
    const float* __restrict__ battn, void* __restrict__ out0, u16* __restrict__ out1)
{
  constexpr int NX = (MODE==1) ? 3 : 2;
  float* Asf = (float*)smem;                           // MODE0/1: f32[128][64] = 32 KB
  u16*  Asb  = (u16*)smem;                             // MODE2:   bf16[128][64] = 16 KB
  u32*  Bs   = smem + ((MODE==2) ? 4096 : 8192);       // bf16[128][64] = 16 KB

  const int tid = threadIdx.x;
  const int x = (g>>3) % NX;
  const int y = ((g>>3)/NX)*8 + (g&7);   // XCD-paired: col-blocks of one A-panel 8 apart -> same XCD
  const int m0 = y * BM;
  const int n0 = x * BN;
  const int lane = tid & 63;
  const int wid  = tid >> 6;
  const int wm = wid >> 1, wn = wid & 1;
  const int ln15 = lane & 15, ln4 = lane >> 4;

  f32x4 acc[4][4];
  #pragma unroll
  for (int i=0;i<4;++i){
    #pragma unroll
    for (int j=0;j<4;++j) acc[i][j] = (f32x4){0.f,0.f,0.f,0.f};
  }

  for (int kt=0; kt<4; ++kt) {
    const int k0 = kt*BK;
    // ---- B loads into regs (issued first; their wait leaves the A-DMA in flight) ----
    f32x4 bvv[8];
    #pragma unroll
    for (int i=0;i<8;++i){
      const int ct = tid + 256*i;
      const int row = ct >> 4, c = ct & 15;
      const int n = n0 + row;
      f32x4 vv = (f32x4){0.f,0.f,0.f,0.f};
      if constexpr (MODE==1) {
        if (n < 192)      vv = *(const f32x4*)(Wmain + (size_t)n*C_ + k0 + c*4);
        else if (n < 288) vv = *(const f32x4*)(Wattn + (size_t)(n-192)*C_ + k0 + c*4);
      } else {
        vv = *(const f32x4*)(Wmain + (size_t)n*C_ + k0 + c*4);
      }
      bvv[i] = vv;
    }
    // ---- A async DMA to LDS (linear dest, inverse-swizzled source) ----
    if constexpr (MODE==2) {
      const u16* Ab = (const u16*)Aany;
      #pragma unroll
      for (int i=0;i<4;++i){
        const int rl = wid*32 + i*8 + (lane>>3);
        const int rg = min(m0 + rl, BS_-1);
        const int c = lane & 7, cs = c ^ (rl & 7);
        const u16* src = Ab + (size_t)rg*C_ + k0 + cs*8;
        __builtin_amdgcn_global_load_lds(src, &Asb[(wid*32 + i*8)*64], 16, 0, 0);
      }
    } else {
      const float* Ab = (const float*)Aany;
      #pragma unroll
      for (int i=0;i<8;++i){
        const int rl = wid*32 + i*4 + (lane>>4);
        const int rg = min(m0 + rl, BS_-1);
        const int c = lane & 15, cs = c ^ (rl & 15);
        const float* src = Ab + (size_t)rg*C_ + k0 + cs*4;
        __builtin_amdgcn_global_load_lds(src, &Asf[(wid*32 + i*4)*64], 16, 0, 0);
      }
    }
    // ---- B cvt + swizzled LDS write ----
    #pragma unroll
    for (int i=0;i<8;++i){
      const int ct = tid + 256*i;
      const int row = ct >> 4, c = ct & 15;
      const u32 p0 = cvtpk(bvv[i].x, bvv[i].y), p1 = cvtpk(bvv[i].z, bvv[i].w);
      const int cc = c >> 1;
      uint2v pk; pk.x = p0; pk.y = p1;
      *(uint2v*)&Bs[row*32 + ((cc ^ (row&7))<<2) + (c&1)*2] = pk;
    }
    __syncthreads();   // drains A-DMA (vmcnt) + B writes (lgkmcnt)
    // ---- compute: 2 k-sub of 32, 4x4 frags ----
    #pragma unroll
    for (int ks=0; ks<2; ++ks) {
      short8v af[4], bfr[4];
      #pragma unroll
      for (int mi=0;mi<4;++mi){
        const int row = wm*64 + mi*16 + ln15;
        if constexpr (MODE==2) {
          const int c = ks*4 + ln4;
          af[mi] = *(const short8v*)&Asb[row*64 + ((c ^ (row&7))<<3)];
        } else {
          const int ch = ks*8 + ln4*2;
          const int c1 = ch ^ (row&15), c2 = (ch+1) ^ (row&15);
          const f32x4 lo = *(const f32x4*)&Asf[row*64 + c1*4];
          const f32x4 hi = *(const f32x4*)&Asf[row*64 + c2*4];
          uint4v uu;
          uu.x = cvtpk(lo.x, lo.y); uu.y = cvtpk(lo.z, lo.w);
          uu.z = cvtpk(hi.x, hi.y); uu.w = cvtpk(hi.z, hi.w);
          af[mi] = __builtin_bit_cast(short8v, uu);
        }
      }
      #pragma unroll
      for (int ni=0;ni<4;++ni){
        const int row = wn*64 + ni*16 + ln15;
        const int c = ks*4 + ln4;
        bfr[ni] = *(const short8v*)&Bs[row*32 + ((c ^ (row&7))<<2)];
      }
      #pragma unroll
      for (int mi=0;mi<4;++mi){
        #pragma unroll
        for (int ni=0;ni<4;++ni)
          acc[mi][ni] = __builtin_amdgcn_mfma_f32_16x16x32_bf16(af[mi], bfr[ni], acc[mi][ni], 0, 0, 0);
      }
    }
    __syncthreads();
  }

  // ---- epilogue (validated rounds 2/4) ----
  #pragma unroll
  for (int mi=0;mi<4;++mi){
    #pragma unroll
    for (int ni=0;ni<4;++ni){
      const int n = n0 + wn*64 + ni*16 + ln15;
      if (MODE==1 && n >= 288) continue;
      float bias;
      if constexpr (MODE==1) bias = (n < 192) ? bmain[n] : battn[n-192];
      else                   bias = bmain[n];
      if (MODE==1 && n >= 192) {
        #pragma unroll
        for (int j=0;j<4;++j){
          const int m = m0 + wm*64 + mi*16 + ln4*4 + j;
          const float vv = acc[mi][ni][j] + bias;
          float mx = vv;
          mx = fmaxf(mx, __shfl_xor(mx, 1));
          mx = fmaxf(mx, __shfl_xor(mx, 2));
          const float e = __expf(vv - mx);
          float ssum = e;
          ssum += __shfl_xor(ssum, 1);
          ssum += __shfl_xor(ssum, 2);
          if (m < BS_) out1[(size_t)m*96 + (n-192)] = f2bf(e/ssum);
        }
      } else if (MODE==1) {
        u16* soff = (u16*)out0;
        #pragma unroll
        for (int j=0;j<4;++j){
          const int m = m0 + wm*64 + mi*16 + ln4*4 + j;
          if (m < BS_) soff[(size_t)m*192 + n] = f2bf(acc[mi][ni][j] + bias);
        }
      } else if (MODE==0) {
        u16* vout = (u16*)out0;
        const int h = n >> 5, dh = n & 31;
        #pragma unroll
        for (int j=0;j<4;++j){
          const int m = m0 + wm*64 + mi*16 + ln4*4 + j;
          if (m < BS_) {
            const int bq = m / S_, s = m - bq*S_;
            vout[((size_t)(bq*NH+h)*S_ + s)*DH + dh] = f2bf(acc[mi][ni][j] + bias);
          }
        }
      } else {
        float* outp = (float*)out0;
        #pragma unroll
        for (int j=0;j<4;++j){
          const int m = m0 + wm*64 + mi*16 + ln4*4 + j;
          if (m < BS_) outp[(size_t)m*C_ + n] = acc[mi][ni][j] + bias;
        }
      }
    }
  }
}

// ---- FUSED projections: blocks [0,1248) = vproj (MODE0), [1248,3120) = qproj (MODE1).
// Independent GEMMs co-resident on CUs -> latency holes of one filled by the other.
__global__ __launch_bounds__(256) void k_proj(
    const void* __restrict__ value, const float* __restrict__ Wv,
    const float* __restrict__ bv, void* __restrict__ vout,
    const void* __restrict__ query, const float* __restrict__ Wo,
    const float* __restrict__ Wa, const float* __restrict__ bo,
    const float* __restrict__ ba, void* __restrict__ soff, u16* __restrict__ sattn)
{
  __shared__ u32 smem[12288];   // 48 KB shared by both instantiations
  const int g = blockIdx.x;
  if (g < 2*624) gemm_core<0>(g,        smem, value, Wv, nullptr, bv, nullptr, vout, nullptr);
  else           gemm_core<1>(g - 2*624, smem, query, Wo, Wa,     bo, ba,      soff, sattn);
}

__global__ __launch_bounds__(256) void k_gemm2(const void* __restrict__ A,
    const float* __restrict__ W, const float* __restrict__ b, void* __restrict__ o)
{
  __shared__ u32 smem[8192];    // 32 KB
  gemm_core<2>(blockIdx.x, smem, A, W, nullptr, b, nullptr, o, nullptr);
}

// ================= Sampler v3 (round-4 proven, 137 us): 8 ch/thread =================
#define NCH 312   // ceil(19950/64) chunks of 64 queries

__global__ __launch_bounds__(256) void k_sample3(const u16* __restrict__ v,
    const u16* __restrict__ soff, const u16* __restrict__ sattn,
    const float* __restrict__ refp, u16* __restrict__ tmp)
{
  const int g = blockIdx.x;
  const int xcd = g & 7, inner = g >> 3;      // inner in [0, 4*NCH)
  const int unit = inner / NCH;               // 0..3
  const int cidx = inner - unit*NCH;
  const int bh = xcd*4 + unit;                // 4 (b,h)-slices per XCD for L2 locality
  const int b = bh >> 3, h = bh & 7;
  const int dh0 = (threadIdx.x & 3) * 8;
  const int q = cidx*64 + (threadIdx.x >> 2);
  if (q >= S_) return;
  const size_t r = (size_t)b*S_ + q;
  const float refx = refp[r*2+0], refy = refp[r*2+1];
  const u16* vb = v + (size_t)bh * S_ * DH;

  const u16* sop = soff + r*192 + h*24;
  const u16* sap = sattn + r*96 + h*12;
  us8 so0 = *(const us8*)(sop);
  us8 so1 = *(const us8*)(sop + 8);
  us8 so2 = *(const us8*)(sop + 16);
  us4 sa0 = *(const us4*)(sap);
  us4 sa1 = *(const us4*)(sap + 4);
  us4 sa2 = *(const us4*)(sap + 8);
  u16 soarr[24]; u16 saarr[12];
  #pragma unroll
  for (int i=0;i<8;++i){ soarr[i]=so0[i]; soarr[8+i]=so1[i]; soarr[16+i]=so2[i]; }
  #pragma unroll
  for (int i=0;i<4;++i){ saarr[i]=sa0[i]; saarr[4+i]=sa1[i]; saarr[8+i]=sa2[i]; }

  f32x2 acc0 = (f32x2){0.f,0.f}, acc1 = acc0, acc2 = acc0, acc3 = acc0;
  const int WLs[3]={152,76,38}, HLs[3]={100,50,25}, STs[3]={0,15200,19000};
  #pragma unroll
  for (int l=0;l<3;++l) {
    const int Wl=WLs[l], Hl=HLs[l];
    const float rxl = refx*(float)Wl - 0.5f;   // ix = ref*W + off - 0.5 (normalizer folded)
    const float ryl = refy*(float)Hl - 0.5f;
    const u16* vbl = vb + (size_t)STs[l]*DH;
    #pragma unroll
    for (int p=0;p<4;++p) {
      const int idx = l*4 + p;
      const float ix = rxl + bf2f(soarr[2*idx+0]);
      const float iy = ryl + bf2f(soarr[2*idx+1]);
      const float aw = bf2f(saarr[idx]);
      const float x0f = floorf(ix), y0f = floorf(iy);
      const float wx1 = ix-x0f, wy1 = iy-y0f;
      const float wx0 = 1.f-wx1, wy0 = 1.f-wy1;
      const int x0 = (int)x0f, y0 = (int)y0f;
      #pragma unroll
      for (int dy=0; dy<2; ++dy) {
        const int yc = y0+dy;
        const bool vy = (yc>=0) && (yc<Hl);
        const int yi = min(max(yc,0),Hl-1);
        const float wyf = aw * (dy?wy1:wy0);
        #pragma unroll
        for (int dx=0; dx<2; ++dx) {
          const int xc = x0+dx;
          const bool vx = (xc>=0) && (xc<Wl);
          const int xi = min(max(xc,0),Wl-1);
          float w = wyf * (dx?wx1:wx0);
          if (!(vx && vy)) w = 0.f;
          f32x2 w2; w2.x = w; w2.y = w;
          const uint4v t = *(const uint4v*)(vbl + (size_t)(yi*Wl + xi)*DH + dh0);
          acc0 = pkfma(unpk(t.x), w2, acc0);
          acc1 = pkfma(unpk(t.y), w2, acc1);
          acc2 = pkfma(unpk(t.z), w2, acc2);
          acc3 = pkfma(unpk(t.w), w2, acc3);
        }
      }
    }
  }
  uint4v o;
  o.x = cvtpk(acc0.x, acc0.y); o.y = cvtpk(acc1.x, acc1.y);
  o.z = cvtpk(acc2.x, acc2.y); o.w = cvtpk(acc3.x, acc3.y);
  *(uint4v*)(tmp + r*C_ + (size_t)h*DH + dh0) = o;
}

extern "C" void kernel_launch(void* const* d_in, const int* in_sizes, int n_in,
                              void* d_out, int out_size, void* d_ws, size_t ws_size,
                              hipStream_t stream) {
  (void)in_sizes; (void)n_in; (void)out_size; (void)ws_size;
  const float* query = (const float*)d_in[0];
  const float* value = (const float*)d_in[1];
  const float* refp  = (const float*)d_in[4];
  const float* W_off = (const float*)d_in[5];
  const float* b_off = (const float*)d_in[6];
  const float* W_attn= (const float*)d_in[7];
  const float* b_attn= (const float*)d_in[8];
  const float* W_val = (const float*)d_in[9];
  const float* b_val = (const float*)d_in[10];
  const float* W_out = (const float*)d_in[11];
  const float* b_out = (const float*)d_in[12];
  float* out = (float*)d_out;

  char* ws = (char*)d_ws;
  constexpr size_t V_BYTES    = (size_t)BS_*C_*2;     // 40.9 MB: v bf16 (b,h,s,dh)
  constexpr size_t SOFF_BYTES = (size_t)BS_*192*2;    // 30.6 MB
  constexpr size_t SATTN_BYTES= (size_t)BS_*96*2;     // 15.3 MB
  u16* v     = (u16*)(ws);
  u16* soff  = (u16*)(ws + V_BYTES);
  u16* sattn = (u16*)(ws + V_BYTES + SOFF_BYTES);
  u16* tmp   = (u16*)(ws + V_BYTES + SOFF_BYTES + SATTN_BYTES);

  dim3 blk(256);
  hipLaunchKernelGGL(k_proj, dim3(5*624), blk, 0, stream,
                     (const void*)value, W_val, b_val, (void*)v,
                     (const void*)query, W_off, W_attn, b_off, b_attn,
                     (void*)soff, sattn);
  hipLaunchKernelGGL(k_sample3, dim3(8*4*NCH), blk, 0, stream, v, soff, sattn, refp, tmp);
  hipLaunchKernelGGL(k_gemm2, dim3(2*624), blk, 0, stream,
                     (const void*)tmp, W_out, b_out, (void*)out);
}